// Round 4
// baseline (797.920 us; speedup 1.0000x reference)
//
#include <hip/hip_runtime.h>

// ResUpBlock via bf16 MFMA implicit GEMM, sub-pixel (phase) decomposition of up2+conv.
//   xT  = channels-last bf16 x                       [8][64][64][256]
//   t1  = lrelu(conv3x3(x,w1/48)+b1)*sqrt2 bf16      [8][64][64][256]
//   t2  = conv1x1(x, wsk/16) bf16                    [8][4096][128]
//   out = up2(t2)/sqrt2                              (k_upskip)
//   out += lrelu(conv3x3(up2(t1),w2/48)+b2)  ==  4-phase conv on t1 with
//          Weff[v][ph] = (Ry[v][py] x Rx[px]) * w2s  (v: y-border variants),
//          x-border outputs (ox in {0,1,126,127}) -> preB raw, fixed by k_corrx.
// R4 fix: k_wselx l==3 correction weight is wp[1]-wp[2] (u[127] clamp AND u[128]
//          conv-pad both deviate), was wp[1] -> absmax 0.445 at ox=127 column.

typedef __attribute__((ext_vector_type(8))) short bf16x8;
typedef __attribute__((ext_vector_type(4))) float f32x4;

#define SQRT2F  1.41421356237309504880f
#define RSQRT2F 0.70710678118654752440f

__device__ __forceinline__ float lrelu_s(float v) { return v >= 0.f ? v : 0.2f * v; }

__device__ __forceinline__ unsigned short f2bf(float f) {
    unsigned u = __builtin_bit_cast(unsigned, f);
    u += 0x7fffu + ((u >> 16) & 1u);          // RNE
    return (unsigned short)(u >> 16);
}
__device__ __forceinline__ float bflo(unsigned u) { return __builtin_bit_cast(float, u << 16); }
__device__ __forceinline__ float bfhi(unsigned u) { return __builtin_bit_cast(float, u & 0xffff0000u); }

__device__ __forceinline__ void up2_coef(int o, int lim, int& i0, int& i1, float& w0, float& w1) {
    int h = o >> 1;
    if (o & 1) { i0 = h; i1 = (h + 1 > lim) ? lim : h + 1; w0 = 0.75f; w1 = 0.25f; }
    else       { i0 = (h - 1 < 0) ? 0 : h - 1; i1 = h;     w0 = 0.25f; w1 = 0.75f; }
}

// upsample row-combination matrices: R[p][d][j] = coeff of t[y-1+j] in u[2y+p+d-1]
// RY variants: 0=interior, 1=first (y=0, true clamp+conv-zero-pad), 2=last (y=63)
static __device__ const float RY_t[3][2][3][3] = {
    { {{0.75f,0.25f,0.f},{0.25f,0.75f,0.f},{0.f,0.75f,0.25f}},
      {{0.25f,0.75f,0.f},{0.f,0.75f,0.25f},{0.f,0.25f,0.75f}} },
    { {{0.f,0.f,0.f},{0.f,1.f,0.f},{0.f,0.75f,0.25f}},
      {{0.f,1.f,0.f},{0.f,0.75f,0.25f},{0.f,0.25f,0.75f}} },
    { {{0.75f,0.25f,0.f},{0.25f,0.75f,0.f},{0.f,1.f,0.f}},
      {{0.25f,0.75f,0.f},{0.f,1.f,0.f},{0.f,0.f,0.f}} }
};

// ---------------------------------------------------------------------------
// weight transforms
// ---------------------------------------------------------------------------
__global__ __launch_bounds__(256) void k_wt3(const float* __restrict__ w,
                                             unsigned short* __restrict__ wt,
                                             int total, float scale) {
    int i = blockIdx.x * 256 + threadIdx.x;           // [oc][tap][c]
    if (i >= total) return;
    int c = i & 255; int rem = i >> 8; int tap = rem % 9; int oc = rem / 9;
    wt[i] = f2bf(w[(oc * 256 + c) * 9 + tap] * scale);
}

__global__ __launch_bounds__(256) void k_wt1(const float* __restrict__ w,
                                             unsigned short* __restrict__ wt,
                                             int total, float scale) {
    int i = blockIdx.x * 256 + threadIdx.x;
    if (i >= total) return;
    wt[i] = f2bf(w[i] * scale);
}

// Wp[v3][ph4][oc128][tap9][c256] = phase-effective weights (1/48 folded)
__global__ __launch_bounds__(256) void k_wphase(const float* __restrict__ w2,
                                                unsigned short* __restrict__ Wp) {
    int i = blockIdx.x * 256 + threadIdx.x;           // 393216
    int c = i & 255, oc = (i >> 8) & 127, ph = (i >> 15) & 3, v = i >> 17;
    int py = ph >> 1, px = ph & 1;
    float wv[9];
#pragma unroll
    for (int t = 0; t < 9; ++t) wv[t] = w2[((oc << 8) + c) * 9 + t] * (1.0f / 48.0f);
#pragma unroll
    for (int jy = 0; jy < 3; ++jy)
#pragma unroll
    for (int jx = 0; jx < 3; ++jx) {
        float s = 0.f;
#pragma unroll
        for (int dv = 0; dv < 3; ++dv)
#pragma unroll
        for (int dh = 0; dh < 3; ++dh)
            s += wv[dv * 3 + dh] * RY_t[v][py][dv][jy] * RY_t[0][px][dh][jx];
        Wp[((size_t)(((v * 4 + ph) * 128 + oc) * 9) + jy * 3 + jx) * 256 + c] = f2bf(s);
    }
}

// wsX[l4][oc128][dv3][c256]: x-border correction weights, l: ox={0,1,126,127}
// Delta(ox=0)  = 0.25*Sum_dv (w[dv][1]-w[dv][0]) * uY[oy-1+dv][0]
// Delta(ox=1)  = 0.25*Sum_dv  w[dv][0]           * uY[oy-1+dv][0]
// Delta(ox=126)= 0.25*Sum_dv  w[dv][2]           * uY[oy-1+dv][63]
// Delta(ox=127)= 0.25*Sum_dv (w[dv][1]-w[dv][2]) * uY[oy-1+dv][63]
__global__ __launch_bounds__(256) void k_wselx(const float* __restrict__ w2,
                                               unsigned short* __restrict__ wsX) {
    int i = blockIdx.x * 256 + threadIdx.x;           // 393216
    int c = i & 255; int j = i >> 8; int dv = j % 3; int j2 = j / 3;
    int oc = j2 & 127; int l = j2 >> 7;
    const float* wp = w2 + ((oc << 8) + c) * 9 + dv * 3;
    float v;
    if (l == 0)      v = wp[1] - wp[0];
    else if (l == 1) v = wp[0];
    else if (l == 2) v = wp[2];
    else             v = wp[1] - wp[2];
    wsX[((size_t)(l * 128 + oc) * 3 + dv) * 256 + c] = f2bf(v * (0.25f / 48.0f));
}

// ---------------------------------------------------------------------------
// x (NCHW f32) -> xT (channels-last bf16)
// ---------------------------------------------------------------------------
__global__ __launch_bounds__(256) void k_xprep(const float* __restrict__ x,
                                               unsigned short* __restrict__ xT) {
    __shared__ float t[64][65];
    const int n = blockIdx.z, c0 = blockIdx.y << 6, p0 = blockIdx.x << 6;
    for (int i = threadIdx.x; i < 4096; i += 256) {
        int c = i >> 6, p = i & 63;
        t[c][p] = x[((size_t)(n * 256 + c0 + c) << 12) + p0 + p];
    }
    __syncthreads();
    for (int i = threadIdx.x; i < 4096; i += 256) {
        int p = i >> 6, c = i & 63;
        xT[((size_t)((n << 12) + p0 + p) << 8) + c0 + c] = f2bf(t[c][p]);
    }
}

// ---------------------------------------------------------------------------
// conv1: t1 = lrelu(conv3x3(x)+b1)*sqrt2, M=128oc x N=128px, grid (256,2)
// ---------------------------------------------------------------------------
__global__ __launch_bounds__(256, 2) void k_conv1(
    const unsigned short* __restrict__ xT, const unsigned short* __restrict__ w1T,
    const float* __restrict__ b1, unsigned short* __restrict__ t1)
{
    __shared__ __align__(16) unsigned short dt[2][10560];   // 2 x [4r][66col][40c]
    const int tid = threadIdx.x;
    const int n   = blockIdx.x >> 5;
    const int y0  = (blockIdx.x & 31) << 1;
    const int oc0 = blockIdx.y << 7;
    const int w = tid >> 6, m = tid & 15, q = (tid & 63) >> 4;
    const int wrow = w >> 1, wxh = (w & 1) << 5;

    int gofs[5], lofs[5]; bool inb[5], act[5];
#pragma unroll
    for (int s = 0; s < 5; ++s) {
        int item = tid + (s << 8);
        act[s] = item < 1056;
        int r = item / 264, rem = item - r * 264, col = rem >> 2, g = rem & 3;
        int gy = y0 - 1 + r, gx = col - 1;
        inb[s] = act[s] && (unsigned)gy < 64u && (unsigned)gx < 64u;
        gofs[s] = (((n << 12) + (gy << 6) + gx) << 8) + (g << 3);
        lofs[s] = (r * 66 + col) * 40 + (g << 3);
    }

    f32x4 acc[8][2];
#pragma unroll
    for (int a = 0; a < 8; ++a)
#pragma unroll
        for (int g = 0; g < 2; ++g) acc[a][g] = (f32x4){0.f, 0.f, 0.f, 0.f};

    const unsigned short* wb = w1T + (size_t)(oc0 + m) * 2304 + (q << 3);

    uint4 stg[5];
#pragma unroll
    for (int s = 0; s < 5; ++s)
        stg[s] = inb[s] ? *(const uint4*)(xT + gofs[s]) : make_uint4(0, 0, 0, 0);

    int buf = 0;
    for (int ch = 0; ch < 8; ++ch) {
        const int c0 = ch << 5;
#pragma unroll
        for (int s = 0; s < 5; ++s)
            if (act[s]) *(uint4*)(&dt[buf][lofs[s]]) = stg[s];
        __syncthreads();
        if (ch < 7) {
            const int c1 = c0 + 32;
#pragma unroll
            for (int s = 0; s < 5; ++s)
                stg[s] = inb[s] ? *(const uint4*)(xT + gofs[s] + c1) : make_uint4(0, 0, 0, 0);
        }
        uint4 aq[2][8];
#pragma unroll
        for (int a = 0; a < 8; ++a)
            aq[0][a] = *(const uint4*)(wb + a * 36864 + c0);
#pragma unroll
        for (int tap = 0; tap < 9; ++tap) {
            const int cur = tap & 1;
            if (tap < 8) {
#pragma unroll
                for (int a = 0; a < 8; ++a)
                    aq[cur ^ 1][a] = *(const uint4*)(wb + a * 36864 + (tap + 1) * 256 + c0);
            }
            const int dy = tap / 3, dx = tap - 3 * dy;
            bf16x8 bfr[2];
#pragma unroll
            for (int g = 0; g < 2; ++g)
                bfr[g] = *(const bf16x8*)(&dt[buf][((wrow + dy) * 66 + (wxh + (g << 4) + m + dx)) * 40 + (q << 3)]);
#pragma unroll
            for (int a = 0; a < 8; ++a) {
                bf16x8 af = __builtin_bit_cast(bf16x8, aq[cur][a]);
#pragma unroll
                for (int g = 0; g < 2; ++g)
                    acc[a][g] = __builtin_amdgcn_mfma_f32_16x16x32_bf16(af, bfr[g], acc[a][g], 0, 0, 0);
            }
        }
        buf ^= 1;
    }

    const int y = y0 + wrow;
#pragma unroll
    for (int a = 0; a < 8; ++a) {
        const int oc = oc0 + (a << 4) + (q << 2);
        float b0 = b1[oc], c1v = b1[oc + 1], c2v = b1[oc + 2], c3v = b1[oc + 3];
#pragma unroll
        for (int g = 0; g < 2; ++g) {
            const int x = wxh + (g << 4) + m;
            unsigned lo = (unsigned)f2bf(lrelu_s(acc[a][g][0] + b0) * SQRT2F)
                        | ((unsigned)f2bf(lrelu_s(acc[a][g][1] + c1v) * SQRT2F) << 16);
            unsigned hi = (unsigned)f2bf(lrelu_s(acc[a][g][2] + c2v) * SQRT2F)
                        | ((unsigned)f2bf(lrelu_s(acc[a][g][3] + c3v) * SQRT2F) << 16);
            uint2 st; st.x = lo; st.y = hi;
            *(uint2*)(t1 + (((size_t)(n << 12) + (y << 6) + x) << 8) + oc) = st;
        }
    }
}

// ---------------------------------------------------------------------------
// skip GEMM: t2[px][oc] = conv1x1(x)  grid 512
// ---------------------------------------------------------------------------
__global__ __launch_bounds__(256, 2) void k_skip(
    const unsigned short* __restrict__ xT, const unsigned short* __restrict__ wsT,
    unsigned short* __restrict__ t2)
{
    const int tid = threadIdx.x;
    const int w = tid >> 6, m = tid & 15, q = (tid & 63) >> 4;
    const int px0 = blockIdx.x << 6;
    const int apx = px0 + (w << 4) + m;

    f32x4 acc[8];
#pragma unroll
    for (int g = 0; g < 8; ++g) acc[g] = (f32x4){0.f, 0.f, 0.f, 0.f};

#pragma unroll
    for (int c0 = 0; c0 < 256; c0 += 32) {
        bf16x8 af = *(const bf16x8*)(xT + ((size_t)apx << 8) + c0 + (q << 3));
#pragma unroll
        for (int g = 0; g < 8; ++g) {
            bf16x8 bf = *(const bf16x8*)(wsT + (((g << 4) + m) << 8) + c0 + (q << 3));
            acc[g] = __builtin_amdgcn_mfma_f32_16x16x32_bf16(af, bf, acc[g], 0, 0, 0);
        }
    }
#pragma unroll
    for (int g = 0; g < 8; ++g) {
        const int oc = (g << 4) + m;
#pragma unroll
        for (int r = 0; r < 4; ++r) {
            int opx = px0 + (w << 4) + (q << 2) + r;
            t2[((size_t)opx << 7) + oc] = f2bf(acc[g][r]);
        }
    }
}

// ---------------------------------------------------------------------------
// out = upsample2x(t2)/sqrt2
// ---------------------------------------------------------------------------
__global__ __launch_bounds__(256) void k_upskip(
    const unsigned short* __restrict__ t2, float* __restrict__ out)
{
    const int tid = threadIdx.x;
    const int oc8 = tid & 15, oxi = tid >> 4;
    const int ox = (blockIdx.x << 4) + oxi;
    const int oy = blockIdx.y;
    const int n  = blockIdx.z;

    int ry0, ry1, cx0, cx1; float wy0, wy1, wx0, wx1;
    up2_coef(oy, 63, ry0, ry1, wy0, wy1);
    up2_coef(ox, 63, cx0, cx1, wx0, wx1);

    const unsigned short* base = t2 + ((size_t)n << 19);
    const int co = oc8 << 3;
    uint4 v00 = *(const uint4*)(base + (((ry0 << 6) + cx0) << 7) + co);
    uint4 v01 = *(const uint4*)(base + (((ry0 << 6) + cx1) << 7) + co);
    uint4 v10 = *(const uint4*)(base + (((ry1 << 6) + cx0) << 7) + co);
    uint4 v11 = *(const uint4*)(base + (((ry1 << 6) + cx1) << 7) + co);
    const unsigned* pa = (const unsigned*)&v00; const unsigned* pb = (const unsigned*)&v01;
    const unsigned* pc = (const unsigned*)&v10; const unsigned* pd = (const unsigned*)&v11;

    float* o = out + ((size_t)(((n << 7) + co) << 7) + oy) * 128 + ox;
#pragma unroll
    for (int j = 0; j < 4; ++j) {
        float vlo = wy0 * (wx0 * bflo(pa[j]) + wx1 * bflo(pb[j]))
                  + wy1 * (wx0 * bflo(pc[j]) + wx1 * bflo(pd[j]));
        float vhi = wy0 * (wx0 * bfhi(pa[j]) + wx1 * bfhi(pb[j]))
                  + wy1 * (wx0 * bfhi(pc[j]) + wx1 * bfhi(pd[j]));
        o[(size_t)(2 * j) * 16384]     = vlo * RSQRT2F;
        o[(size_t)(2 * j + 1) * 16384] = vhi * RSQRT2F;
    }
}

// ---------------------------------------------------------------------------
// conv2p: 4-phase conv on t1; interior -> out += lrelu, x-border -> preB raw.
// grid (256, 4): by = phase. M=128 (all oc), N=128 px of t1 grid.
// ---------------------------------------------------------------------------
__global__ __launch_bounds__(256, 2) void k_conv2p(
    const unsigned short* __restrict__ t1, const unsigned short* __restrict__ Wp,
    const float* __restrict__ b2, float* __restrict__ out, float* __restrict__ preB)
{
    __shared__ __align__(16) unsigned short dt[2][10560];
    const int tid = threadIdx.x;
    const int n   = blockIdx.x >> 5;
    const int y0  = (blockIdx.x & 31) << 1;
    const int ph  = blockIdx.y;
    const int py = ph >> 1, pxp = ph & 1;
    const int w = tid >> 6, m = tid & 15, q = (tid & 63) >> 4;
    const int wrow = w >> 1, wxh = (w & 1) << 5;

    int gofs[5], lofs[5]; bool inb[5], act[5];
#pragma unroll
    for (int s = 0; s < 5; ++s) {
        int item = tid + (s << 8);
        act[s] = item < 1056;
        int r = item / 264, rem = item - r * 264, col = rem >> 2, g = rem & 3;
        int gy = y0 - 1 + r, gx = col - 1;
        inb[s] = act[s] && (unsigned)gy < 64u && (unsigned)gx < 64u;
        gofs[s] = (((n << 12) + (gy << 6) + gx) << 8) + (g << 3);
        lofs[s] = (r * 66 + col) * 40 + (g << 3);
    }

    f32x4 acc[8][2];
#pragma unroll
    for (int a = 0; a < 8; ++a)
#pragma unroll
        for (int g = 0; g < 2; ++g) acc[a][g] = (f32x4){0.f, 0.f, 0.f, 0.f};

    const int yw = y0 + wrow;
    const int v = (yw == 0) ? 1 : ((yw == 63) ? 2 : 0);
    const unsigned short* wb = Wp + (size_t)(((v * 4 + ph) << 7) + m) * 2304 + (q << 3);

    uint4 stg[5];
#pragma unroll
    for (int s = 0; s < 5; ++s)
        stg[s] = inb[s] ? *(const uint4*)(t1 + gofs[s]) : make_uint4(0, 0, 0, 0);

    int buf = 0;
    for (int ch = 0; ch < 8; ++ch) {
        const int c0 = ch << 5;
#pragma unroll
        for (int s = 0; s < 5; ++s)
            if (act[s]) *(uint4*)(&dt[buf][lofs[s]]) = stg[s];
        __syncthreads();
        if (ch < 7) {
            const int c1 = c0 + 32;
#pragma unroll
            for (int s = 0; s < 5; ++s)
                stg[s] = inb[s] ? *(const uint4*)(t1 + gofs[s] + c1) : make_uint4(0, 0, 0, 0);
        }
        uint4 aq[2][8];
#pragma unroll
        for (int a = 0; a < 8; ++a)
            aq[0][a] = *(const uint4*)(wb + a * 36864 + c0);
#pragma unroll
        for (int tap = 0; tap < 9; ++tap) {
            const int cur = tap & 1;
            if (tap < 8) {
#pragma unroll
                for (int a = 0; a < 8; ++a)
                    aq[cur ^ 1][a] = *(const uint4*)(wb + a * 36864 + (tap + 1) * 256 + c0);
            }
            const int dy = tap / 3, dx = tap - 3 * dy;
            bf16x8 bfr[2];
#pragma unroll
            for (int g = 0; g < 2; ++g)
                bfr[g] = *(const bf16x8*)(&dt[buf][((wrow + dy) * 66 + (wxh + (g << 4) + m + dx)) * 40 + (q << 3)]);
#pragma unroll
            for (int a = 0; a < 8; ++a) {
                bf16x8 af = __builtin_bit_cast(bf16x8, aq[cur][a]);
#pragma unroll
                for (int g = 0; g < 2; ++g)
                    acc[a][g] = __builtin_amdgcn_mfma_f32_16x16x32_bf16(af, bfr[g], acc[a][g], 0, 0, 0);
            }
        }
        buf ^= 1;
    }

    const int oy = 2 * yw + py;
#pragma unroll
    for (int a = 0; a < 8; ++a) {
        const int oc = (a << 4) + (q << 2);
        float bb[4] = {b2[oc], b2[oc + 1], b2[oc + 2], b2[oc + 3]};
#pragma unroll
        for (int g = 0; g < 2; ++g) {
            const int x = wxh + (g << 4) + m;
            const int ox = 2 * x + pxp;
            const bool bord = (x == 0) || (x == 63);
            const int lb = (x == 0) ? pxp : 2 + pxp;
#pragma unroll
            for (int r = 0; r < 4; ++r) {
                float raw = acc[a][g][r] + bb[r];
                if (bord) {
                    preB[(((size_t)(n << 2) + lb) * 128 + oc + r) * 128 + oy] = raw;
                } else {
                    float* p = out + (((size_t)(n << 7) + oc + r) * 128 + oy) * 128 + ox;
                    *p += lrelu_s(raw);
                }
            }
        }
    }
}

// ---------------------------------------------------------------------------
// corrx: out[.,.,oy,ox_l] += lrelu(preB + DeltaX), DeltaX = wsX * uYt (K=768 GEMM)
// grid 32: (n, l). M=128 oc, N=128 oy.
// ---------------------------------------------------------------------------
__global__ __launch_bounds__(256, 2) void k_corrx(
    const unsigned short* __restrict__ t1, const unsigned short* __restrict__ wsX,
    const float* __restrict__ preB, float* __restrict__ out)
{
    __shared__ __align__(16) unsigned short ub[130 * 40];
    const int tid = threadIdx.x;
    const int n = blockIdx.x >> 2, l = blockIdx.x & 3;
    const int xe  = (l < 2) ? 0 : 63;
    const int oxl = (l < 2) ? l : 124 + l;
    const int w = tid >> 6, m = tid & 15, q = (tid & 63) >> 4;
    const int woc = (w >> 1) << 6, woy = (w & 1) << 6;

    f32x4 acc[4][4];
#pragma unroll
    for (int a = 0; a < 4; ++a)
#pragma unroll
        for (int g = 0; g < 4; ++g) acc[a][g] = (f32x4){0.f, 0.f, 0.f, 0.f};

    const unsigned short* wbs = wsX + (size_t)((l << 7) + woc + m) * 768 + (q << 3);

    for (int ch = 0; ch < 8; ++ch) {
        const int c0 = ch << 5;
        for (int it = tid; it < 520; it += 256) {
            int vidx = it >> 2, g = it & 3;
            int vv = vidx - 1;
            uint4 res = make_uint4(0, 0, 0, 0);
            if ((unsigned)vv < 128u) {
                int k = vv >> 1; int r0, r1; float f0, f1;
                if (vv & 1) { r0 = k; r1 = (k + 1 > 63) ? 63 : k + 1; f0 = 0.75f; f1 = 0.25f; }
                else        { r0 = (k - 1 < 0) ? 0 : k - 1; r1 = k;   f0 = 0.25f; f1 = 0.75f; }
                uint4 u0 = *(const uint4*)(t1 + (((size_t)(n << 12) + (r0 << 6) + xe) << 8) + c0 + (g << 3));
                uint4 u1 = *(const uint4*)(t1 + (((size_t)(n << 12) + (r1 << 6) + xe) << 8) + c0 + (g << 3));
                const unsigned* a0 = (const unsigned*)&u0; const unsigned* a1 = (const unsigned*)&u1;
                unsigned* pr = (unsigned*)&res;
#pragma unroll
                for (int j = 0; j < 4; ++j) {
                    float vl = f0 * bflo(a0[j]) + f1 * bflo(a1[j]);
                    float vh = f0 * bfhi(a0[j]) + f1 * bfhi(a1[j]);
                    pr[j] = (unsigned)f2bf(vl) | ((unsigned)f2bf(vh) << 16);
                }
            }
            *(uint4*)(&ub[vidx * 40 + (g << 3)]) = res;
        }
        __syncthreads();
#pragma unroll
        for (int dv = 0; dv < 3; ++dv) {
            uint4 aq[4];
#pragma unroll
            for (int a = 0; a < 4; ++a)
                aq[a] = *(const uint4*)(wbs + a * (16 * 768) + dv * 256 + c0);
            bf16x8 bfr[4];
#pragma unroll
            for (int g = 0; g < 4; ++g)
                bfr[g] = *(const bf16x8*)(&ub[(woy + (g << 4) + m + dv) * 40 + (q << 3)]);
#pragma unroll
            for (int a = 0; a < 4; ++a) {
                bf16x8 af = __builtin_bit_cast(bf16x8, aq[a]);
#pragma unroll
                for (int g = 0; g < 4; ++g)
                    acc[a][g] = __builtin_amdgcn_mfma_f32_16x16x32_bf16(af, bfr[g], acc[a][g], 0, 0, 0);
            }
        }
        __syncthreads();
    }
#pragma unroll
    for (int a = 0; a < 4; ++a) {
        const int oc = woc + (a << 4) + (q << 2);
#pragma unroll
        for (int g = 0; g < 4; ++g) {
            const int oy = woy + (g << 4) + m;
#pragma unroll
            for (int r = 0; r < 4; ++r) {
                float val = preB[(((size_t)(n << 2) + l) * 128 + oc + r) * 128 + oy] + acc[a][g][r];
                out[(((size_t)(n << 7) + oc + r) * 128 + oy) * 128 + oxl] += lrelu_s(val);
            }
        }
    }
}

// ---------------------------------------------------------------------------
extern "C" void kernel_launch(void* const* d_in, const int* in_sizes, int n_in,
                              void* d_out, int out_size, void* d_ws, size_t ws_size,
                              hipStream_t stream)
{
    const float* x   = (const float*)d_in[0];
    const float* w1  = (const float*)d_in[1];
    const float* b1  = (const float*)d_in[2];
    const float* w2  = (const float*)d_in[3];
    const float* b2  = (const float*)d_in[4];
    const float* wsk = (const float*)d_in[5];
    float* out = (float*)d_out;

    unsigned short* xT  = (unsigned short*)d_ws;        // 8,388,608 elems
    unsigned short* t1  = xT + 8388608;                 // 8,388,608
    unsigned short* t2  = t1 + 8388608;                 // 4,194,304
    unsigned short* w1T = t2 + 4194304;                 // 589,824
    unsigned short* Wp  = w1T + 589824;                 // 3,538,944
    unsigned short* wsX = Wp + 3538944;                 // 393,216
    unsigned short* wsT = wsX + 393216;                 // 32,768
    float* preB = (float*)t2;                            // aliases t2 (dead after k_upskip)

    k_wt3   <<<2304, 256, 0, stream>>>(w1, w1T, 589824, 1.0f / 48.0f);
    k_wphase<<<1536, 256, 0, stream>>>(w2, Wp);
    k_wselx <<<1536, 256, 0, stream>>>(w2, wsX);
    k_wt1   <<<128,  256, 0, stream>>>(wsk, wsT, 32768, 1.0f / 16.0f);
    k_xprep <<<dim3(64, 4, 8), 256, 0, stream>>>(x, xT);
    k_conv1 <<<dim3(256, 2), 256, 0, stream>>>(xT, w1T, b1, t1);
    k_skip  <<<512, 256, 0, stream>>>(xT, wsT, t2);
    k_upskip<<<dim3(8, 128, 8), 256, 0, stream>>>(t2, out);
    k_conv2p<<<dim3(256, 4), 256, 0, stream>>>(t1, Wp, b2, out, preB);
    k_corrx <<<32, 256, 0, stream>>>(t1, wsX, preB, out);
}

// Round 5
// 482.592 us; speedup vs baseline: 1.6534x; 1.6534x over previous
//
#include <hip/hip_runtime.h>

// ResUpBlock, bf16 MFMA implicit GEMM, phase-decomposed up2+conv (verified R4 math),
// R5: m97-style K-loop — BOTH operand tiles in LDS via global_load_lds DMA.
//   A-tile: [tap9][oc64][36pad] bf16 (41.0 KB), linear DMA from pre-padded global slab.
//   B-tile: [4r][66col][40pad]  bf16 (21.0 KB), 16B-unit DMA with zero-guard for halo.
//   Per wave: a=4 (64 oc) x g=2 (32 px), 8 MFMA/tap, A+B = 6 ds_read_b128/tap.
//   conv2p y-border waves (v!=0: rows 0,63) read variant weights from global (rare).

typedef __attribute__((ext_vector_type(8))) short bf16x8;
typedef __attribute__((ext_vector_type(4))) float f32x4;

#define SQRT2F  1.41421356237309504880f
#define RSQRT2F 0.70710678118654752440f

__device__ __forceinline__ float lrelu_s(float v) { return v >= 0.f ? v : 0.2f * v; }

__device__ __forceinline__ unsigned short f2bf(float f) {
    unsigned u = __builtin_bit_cast(unsigned, f);
    u += 0x7fffu + ((u >> 16) & 1u);          // RNE
    return (unsigned short)(u >> 16);
}
__device__ __forceinline__ float bflo(unsigned u) { return __builtin_bit_cast(float, u << 16); }
__device__ __forceinline__ float bfhi(unsigned u) { return __builtin_bit_cast(float, u & 0xffff0000u); }

// 16B global->LDS DMA; HW writes lds_base(wave-uniform) + lane*16
__device__ __forceinline__ void dma16(const unsigned short* g, unsigned short* l) {
    __builtin_amdgcn_global_load_lds(
        (const __attribute__((address_space(1))) unsigned int*)g,
        (__attribute__((address_space(3))) unsigned int*)l, 16, 0, 0);
}

__device__ __forceinline__ void up2_coef(int o, int lim, int& i0, int& i1, float& w0, float& w1) {
    int h = o >> 1;
    if (o & 1) { i0 = h; i1 = (h + 1 > lim) ? lim : h + 1; w0 = 0.75f; w1 = 0.25f; }
    else       { i0 = (h - 1 < 0) ? 0 : h - 1; i1 = h;     w0 = 0.25f; w1 = 0.75f; }
}

// upsample row-combination matrices: R[p][d][j] = coeff of t[y-1+j] in u[2y+p+d-1]
// variants: 0=interior, 1=first (y=0), 2=last (y=63)
static __device__ const float RY_t[3][2][3][3] = {
    { {{0.75f,0.25f,0.f},{0.25f,0.75f,0.f},{0.f,0.75f,0.25f}},
      {{0.25f,0.75f,0.f},{0.f,0.75f,0.25f},{0.f,0.25f,0.75f}} },
    { {{0.f,0.f,0.f},{0.f,1.f,0.f},{0.f,0.75f,0.25f}},
      {{0.f,1.f,0.f},{0.f,0.75f,0.25f},{0.f,0.25f,0.75f}} },
    { {{0.75f,0.25f,0.f},{0.25f,0.75f,0.f},{0.f,1.f,0.f}},
      {{0.25f,0.75f,0.f},{0.f,1.f,0.f},{0.f,0.f,0.f}} }
};

// ---------------------------------------------------------------------------
// weight transforms (new padded layouts for DMA)
// ---------------------------------------------------------------------------
// w1T[ocb4][ch8][tap9][oc64][36]: chunk slab = 20736 sh contiguous
__global__ __launch_bounds__(256) void k_wt3(const float* __restrict__ w,
                                             unsigned short* __restrict__ wt) {
    int i = blockIdx.x * 256 + threadIdx.x;           // over 256 oc x 9 tap x 256 c
    if (i >= 589824) return;
    int c = i & 255; int rem = i >> 8; int tap = rem % 9; int oc = rem / 9;
    int ocb = oc >> 6, o6 = oc & 63, ch = c >> 5, c5 = c & 31;
    wt[(size_t)(((ocb * 8 + ch) * 9 + tap) * 64 + o6) * 36 + c5] =
        f2bf(w[(oc * 256 + c) * 9 + tap] * (1.0f / 48.0f));
}

__global__ __launch_bounds__(256) void k_wt1(const float* __restrict__ w,
                                             unsigned short* __restrict__ wt,
                                             int total, float scale) {
    int i = blockIdx.x * 256 + threadIdx.x;
    if (i >= total) return;
    wt[i] = f2bf(w[i] * scale);
}

// Wp[v3][ph4][ocb2][ch8][tap9][oc64][36]
__global__ __launch_bounds__(256) void k_wphase(const float* __restrict__ w2,
                                                unsigned short* __restrict__ Wp) {
    int i = blockIdx.x * 256 + threadIdx.x;           // 393216 = 3v x 4ph x 128oc x 256c
    int c = i & 255, oc = (i >> 8) & 127, ph = (i >> 15) & 3, v = i >> 17;
    int py = ph >> 1, px = ph & 1;
    int ocb = oc >> 6, o6 = oc & 63, ch = c >> 5, c5 = c & 31;
    float wv[9];
#pragma unroll
    for (int t = 0; t < 9; ++t) wv[t] = w2[((oc << 8) + c) * 9 + t] * (1.0f / 48.0f);
#pragma unroll
    for (int jy = 0; jy < 3; ++jy)
#pragma unroll
    for (int jx = 0; jx < 3; ++jx) {
        float s = 0.f;
#pragma unroll
        for (int dv = 0; dv < 3; ++dv)
#pragma unroll
        for (int dh = 0; dh < 3; ++dh)
            s += wv[dv * 3 + dh] * RY_t[v][py][dv][jy] * RY_t[0][px][dh][jx];
        Wp[(size_t)((((((v * 4 + ph) * 2 + ocb) * 8 + ch) * 9 + jy * 3 + jx) * 64 + o6)) * 36 + c5] = f2bf(s);
    }
}

// wsX[l4][oc128][dv3][c256]: x-border correction weights (verified R4)
__global__ __launch_bounds__(256) void k_wselx(const float* __restrict__ w2,
                                               unsigned short* __restrict__ wsX) {
    int i = blockIdx.x * 256 + threadIdx.x;           // 393216
    int c = i & 255; int j = i >> 8; int dv = j % 3; int j2 = j / 3;
    int oc = j2 & 127; int l = j2 >> 7;
    const float* wp = w2 + ((oc << 8) + c) * 9 + dv * 3;
    float v;
    if (l == 0)      v = wp[1] - wp[0];
    else if (l == 1) v = wp[0];
    else if (l == 2) v = wp[2];
    else             v = wp[1] - wp[2];
    wsX[((size_t)(l * 128 + oc) * 3 + dv) * 256 + c] = f2bf(v * (0.25f / 48.0f));
}

// ---------------------------------------------------------------------------
// x (NCHW f32) -> xT (channels-last bf16)
// ---------------------------------------------------------------------------
__global__ __launch_bounds__(256) void k_xprep(const float* __restrict__ x,
                                               unsigned short* __restrict__ xT) {
    __shared__ float t[64][65];
    const int n = blockIdx.z, c0 = blockIdx.y << 6, p0 = blockIdx.x << 6;
    for (int i = threadIdx.x; i < 4096; i += 256) {
        int c = i >> 6, p = i & 63;
        t[c][p] = x[((size_t)(n * 256 + c0 + c) << 12) + p0 + p];
    }
    __syncthreads();
    for (int i = threadIdx.x; i < 4096; i += 256) {
        int p = i >> 6, c = i & 63;
        xT[((size_t)((n << 12) + p0 + p) << 8) + c0 + c] = f2bf(t[c][p]);
    }
}

// ---------------------------------------------------------------------------
// conv1: t1 = lrelu(conv3x3(x)+b1)*sqrt2.  grid (256, 4): bx=(n,ytile), by=ocb
// ---------------------------------------------------------------------------
__global__ __launch_bounds__(256, 2) void k_conv1(
    const unsigned short* __restrict__ xT, const unsigned short* __restrict__ w1T,
    const float* __restrict__ b1, unsigned short* __restrict__ t1,
    const unsigned short* __restrict__ guard)
{
    __shared__ __align__(16) unsigned short At[20992];   // [tap9][oc64][36] + DMA slack
    __shared__ __align__(16) unsigned short Bt[10752];   // [4r][66col][40] (1344 units)
    const int tid = threadIdx.x;
    const int n   = blockIdx.x >> 5;
    const int y0  = (blockIdx.x & 31) << 1;
    const int ocb = blockIdx.y;
    const int w = tid >> 6, m = tid & 15, q = (tid & 63) >> 4;
    const int wrow = w >> 1, wxh = (w & 1) << 5;

    // B-tile DMA descriptors: 1320 units (4r x 66col x 5 units/px; unit4 = pad)
    const unsigned short* bsrc[6];
#pragma unroll
    for (int k = 0; k < 6; ++k) {
        int U = tid + (k << 8);
        int px = U / 5, unit = U - px * 5;
        int r = px / 66, col = px - r * 66;
        int gy = y0 - 1 + r, gx = col - 1;
        bool val = (U < 1320) && (unit < 4) && ((unsigned)gy < 64u) && ((unsigned)gx < 64u);
        bsrc[k] = val ? xT + (((size_t)(n << 12) + (gy << 6) + gx) << 8) + (unit << 3)
                      : (const unsigned short*)0;
    }
    const unsigned short* wslab = w1T + (size_t)ocb * (8 * 20736);

    f32x4 acc[4][2];
#pragma unroll
    for (int a = 0; a < 4; ++a)
#pragma unroll
        for (int g = 0; g < 2; ++g) acc[a][g] = (f32x4){0.f, 0.f, 0.f, 0.f};

    for (int ch = 0; ch < 8; ++ch) {
        // B DMA (first: slower source), then A DMA (L2-hot weights)
#pragma unroll
        for (int k = 0; k < 6; ++k) {
            int u0 = (w << 6) + (k << 8);
            if (u0 < 1344) {
                const unsigned short* g = bsrc[k] ? bsrc[k] + (ch << 5) : guard;
                dma16(g, &Bt[(size_t)u0 << 3]);
            }
        }
        const unsigned short* wsl = wslab + ch * 20736;
#pragma unroll
        for (int k = 0; k < 11; ++k) {
            int u0 = (w << 6) + (k << 8);
            if (u0 < 2592) {
                int U = tid + (k << 8);
                const unsigned short* g = (U < 2592) ? wsl + ((size_t)U << 3) : guard;
                dma16(g, &At[(size_t)u0 << 3]);
            }
        }
        __syncthreads();
#pragma unroll
        for (int tap = 0; tap < 9; ++tap) {
            const int dy = tap / 3, dx = tap - 3 * dy;
            bf16x8 aq[4], bfr[2];
#pragma unroll
            for (int a = 0; a < 4; ++a)
                aq[a] = *(const bf16x8*)&At[tap * 2304 + ((a << 4) + m) * 36 + (q << 3)];
#pragma unroll
            for (int g = 0; g < 2; ++g)
                bfr[g] = *(const bf16x8*)&Bt[((wrow + dy) * 66 + (wxh + (g << 4) + m + dx)) * 40 + (q << 3)];
#pragma unroll
            for (int a = 0; a < 4; ++a)
#pragma unroll
                for (int g = 0; g < 2; ++g)
                    acc[a][g] = __builtin_amdgcn_mfma_f32_16x16x32_bf16(aq[a], bfr[g], acc[a][g], 0, 0, 0);
        }
        __syncthreads();
    }

    const int y = y0 + wrow;
#pragma unroll
    for (int a = 0; a < 4; ++a) {
        const int oc = (ocb << 6) + (a << 4) + (q << 2);
        float b0 = b1[oc], c1v = b1[oc + 1], c2v = b1[oc + 2], c3v = b1[oc + 3];
#pragma unroll
        for (int g = 0; g < 2; ++g) {
            const int x = wxh + (g << 4) + m;
            unsigned lo = (unsigned)f2bf(lrelu_s(acc[a][g][0] + b0) * SQRT2F)
                        | ((unsigned)f2bf(lrelu_s(acc[a][g][1] + c1v) * SQRT2F) << 16);
            unsigned hi = (unsigned)f2bf(lrelu_s(acc[a][g][2] + c2v) * SQRT2F)
                        | ((unsigned)f2bf(lrelu_s(acc[a][g][3] + c3v) * SQRT2F) << 16);
            uint2 st; st.x = lo; st.y = hi;
            *(uint2*)(t1 + (((size_t)(n << 12) + (y << 6) + x) << 8) + oc) = st;
        }
    }
}

// ---------------------------------------------------------------------------
// conv2p: 4-phase conv on t1 (interior weights in LDS; y-border waves stream
// their variant weights from global). grid (256, 8): by = ph*2+ocb
// ---------------------------------------------------------------------------
__global__ __launch_bounds__(256, 2) void k_conv2p(
    const unsigned short* __restrict__ t1, const unsigned short* __restrict__ Wp,
    const float* __restrict__ b2, float* __restrict__ out, float* __restrict__ preB,
    const unsigned short* __restrict__ guard)
{
    __shared__ __align__(16) unsigned short At[20992];
    __shared__ __align__(16) unsigned short Bt[10752];
    const int tid = threadIdx.x;
    const int n   = blockIdx.x >> 5;
    const int y0  = (blockIdx.x & 31) << 1;
    const int ph  = blockIdx.y >> 1;
    const int ocb = blockIdx.y & 1;
    const int py = ph >> 1, pxp = ph & 1;
    const int w = tid >> 6, m = tid & 15, q = (tid & 63) >> 4;
    const int wrow = w >> 1, wxh = (w & 1) << 5;

    const unsigned short* bsrc[6];
#pragma unroll
    for (int k = 0; k < 6; ++k) {
        int U = tid + (k << 8);
        int px = U / 5, unit = U - px * 5;
        int r = px / 66, col = px - r * 66;
        int gy = y0 - 1 + r, gx = col - 1;
        bool val = (U < 1320) && (unit < 4) && ((unsigned)gy < 64u) && ((unsigned)gx < 64u);
        bsrc[k] = val ? t1 + (((size_t)(n << 12) + (gy << 6) + gx) << 8) + (unit << 3)
                      : (const unsigned short*)0;
    }
    // interior (v=0) slab staged to LDS; border waves use global slab for their v
    const size_t slabstride = 20736;
    const unsigned short* wslab0 = Wp + ((size_t)((0 * 4 + ph) * 2 + ocb) * 8) * slabstride;
    const int yw = y0 + wrow;
    const int v = (yw == 0) ? 1 : ((yw == 63) ? 2 : 0);
    const unsigned short* wslabv = Wp + ((size_t)((v * 4 + ph) * 2 + ocb) * 8) * slabstride;

    f32x4 acc[4][2];
#pragma unroll
    for (int a = 0; a < 4; ++a)
#pragma unroll
        for (int g = 0; g < 2; ++g) acc[a][g] = (f32x4){0.f, 0.f, 0.f, 0.f};

    for (int ch = 0; ch < 8; ++ch) {
#pragma unroll
        for (int k = 0; k < 6; ++k) {
            int u0 = (w << 6) + (k << 8);
            if (u0 < 1344) {
                const unsigned short* g = bsrc[k] ? bsrc[k] + (ch << 5) : guard;
                dma16(g, &Bt[(size_t)u0 << 3]);
            }
        }
        const unsigned short* wsl = wslab0 + ch * slabstride;
#pragma unroll
        for (int k = 0; k < 11; ++k) {
            int u0 = (w << 6) + (k << 8);
            if (u0 < 2592) {
                int U = tid + (k << 8);
                const unsigned short* g = (U < 2592) ? wsl + ((size_t)U << 3) : guard;
                dma16(g, &At[(size_t)u0 << 3]);
            }
        }
        __syncthreads();
        const unsigned short* wgv = wslabv + ch * slabstride;
#pragma unroll
        for (int tap = 0; tap < 9; ++tap) {
            const int dy = tap / 3, dx = tap - 3 * dy;
            bf16x8 aq[4], bfr[2];
            if (v == 0) {
#pragma unroll
                for (int a = 0; a < 4; ++a)
                    aq[a] = *(const bf16x8*)&At[tap * 2304 + ((a << 4) + m) * 36 + (q << 3)];
            } else {
#pragma unroll
                for (int a = 0; a < 4; ++a)
                    aq[a] = *(const bf16x8*)(wgv + tap * 2304 + ((a << 4) + m) * 36 + (q << 3));
            }
#pragma unroll
            for (int g = 0; g < 2; ++g)
                bfr[g] = *(const bf16x8*)&Bt[((wrow + dy) * 66 + (wxh + (g << 4) + m + dx)) * 40 + (q << 3)];
#pragma unroll
            for (int a = 0; a < 4; ++a)
#pragma unroll
                for (int g = 0; g < 2; ++g)
                    acc[a][g] = __builtin_amdgcn_mfma_f32_16x16x32_bf16(aq[a], bfr[g], acc[a][g], 0, 0, 0);
        }
        __syncthreads();
    }

    const int oy = 2 * yw + py;
#pragma unroll
    for (int a = 0; a < 4; ++a) {
        const int oc = (ocb << 6) + (a << 4) + (q << 2);
        float bb[4] = {b2[oc], b2[oc + 1], b2[oc + 2], b2[oc + 3]};
#pragma unroll
        for (int g = 0; g < 2; ++g) {
            const int x = wxh + (g << 4) + m;
            const int ox = 2 * x + pxp;
            const bool bord = (x == 0) || (x == 63);
            const int lb = (x == 0) ? pxp : 2 + pxp;
#pragma unroll
            for (int r = 0; r < 4; ++r) {
                float raw = acc[a][g][r] + bb[r];
                if (bord) {
                    preB[(((size_t)(n << 2) + lb) * 128 + oc + r) * 128 + oy] = raw;
                } else {
                    float* p = out + (((size_t)(n << 7) + oc + r) * 128 + oy) * 128 + ox;
                    *p += lrelu_s(raw);
                }
            }
        }
    }
}

// ---------------------------------------------------------------------------
// skip GEMM: t2[px][oc] = conv1x1(x)  grid 512
// ---------------------------------------------------------------------------
__global__ __launch_bounds__(256, 2) void k_skip(
    const unsigned short* __restrict__ xT, const unsigned short* __restrict__ wsT,
    unsigned short* __restrict__ t2)
{
    const int tid = threadIdx.x;
    const int w = tid >> 6, m = tid & 15, q = (tid & 63) >> 4;
    const int px0 = blockIdx.x << 6;
    const int apx = px0 + (w << 4) + m;

    f32x4 acc[8];
#pragma unroll
    for (int g = 0; g < 8; ++g) acc[g] = (f32x4){0.f, 0.f, 0.f, 0.f};

#pragma unroll
    for (int c0 = 0; c0 < 256; c0 += 32) {
        bf16x8 af = *(const bf16x8*)(xT + ((size_t)apx << 8) + c0 + (q << 3));
#pragma unroll
        for (int g = 0; g < 8; ++g) {
            bf16x8 bf = *(const bf16x8*)(wsT + (((g << 4) + m) << 8) + c0 + (q << 3));
            acc[g] = __builtin_amdgcn_mfma_f32_16x16x32_bf16(af, bf, acc[g], 0, 0, 0);
        }
    }
#pragma unroll
    for (int g = 0; g < 8; ++g) {
        const int oc = (g << 4) + m;
#pragma unroll
        for (int r = 0; r < 4; ++r) {
            int opx = px0 + (w << 4) + (q << 2) + r;
            t2[((size_t)opx << 7) + oc] = f2bf(acc[g][r]);
        }
    }
}

// ---------------------------------------------------------------------------
// out = upsample2x(t2)/sqrt2
// ---------------------------------------------------------------------------
__global__ __launch_bounds__(256) void k_upskip(
    const unsigned short* __restrict__ t2, float* __restrict__ out)
{
    const int tid = threadIdx.x;
    const int oc8 = tid & 15, oxi = tid >> 4;
    const int ox = (blockIdx.x << 4) + oxi;
    const int oy = blockIdx.y;
    const int n  = blockIdx.z;

    int ry0, ry1, cx0, cx1; float wy0, wy1, wx0, wx1;
    up2_coef(oy, 63, ry0, ry1, wy0, wy1);
    up2_coef(ox, 63, cx0, cx1, wx0, wx1);

    const unsigned short* base = t2 + ((size_t)n << 19);
    const int co = oc8 << 3;
    uint4 v00 = *(const uint4*)(base + (((ry0 << 6) + cx0) << 7) + co);
    uint4 v01 = *(const uint4*)(base + (((ry0 << 6) + cx1) << 7) + co);
    uint4 v10 = *(const uint4*)(base + (((ry1 << 6) + cx0) << 7) + co);
    uint4 v11 = *(const uint4*)(base + (((ry1 << 6) + cx1) << 7) + co);
    const unsigned* pa = (const unsigned*)&v00; const unsigned* pb = (const unsigned*)&v01;
    const unsigned* pc = (const unsigned*)&v10; const unsigned* pd = (const unsigned*)&v11;

    float* o = out + ((size_t)(((n << 7) + co) << 7) + oy) * 128 + ox;
#pragma unroll
    for (int j = 0; j < 4; ++j) {
        float vlo = wy0 * (wx0 * bflo(pa[j]) + wx1 * bflo(pb[j]))
                  + wy1 * (wx0 * bflo(pc[j]) + wx1 * bflo(pd[j]));
        float vhi = wy0 * (wx0 * bfhi(pa[j]) + wx1 * bfhi(pb[j]))
                  + wy1 * (wx0 * bfhi(pc[j]) + wx1 * bfhi(pd[j]));
        o[(size_t)(2 * j) * 16384]     = vlo * RSQRT2F;
        o[(size_t)(2 * j + 1) * 16384] = vhi * RSQRT2F;
    }
}

// ---------------------------------------------------------------------------
// corrx: out[.,.,oy,ox_l] += lrelu(preB + DeltaX)  (verified R4)  grid 32
// ---------------------------------------------------------------------------
__global__ __launch_bounds__(256, 2) void k_corrx(
    const unsigned short* __restrict__ t1, const unsigned short* __restrict__ wsX,
    const float* __restrict__ preB, float* __restrict__ out)
{
    __shared__ __align__(16) unsigned short ub[130 * 40];
    const int tid = threadIdx.x;
    const int n = blockIdx.x >> 2, l = blockIdx.x & 3;
    const int xe  = (l < 2) ? 0 : 63;
    const int oxl = (l < 2) ? l : 124 + l;
    const int w = tid >> 6, m = tid & 15, q = (tid & 63) >> 4;
    const int woc = (w >> 1) << 6, woy = (w & 1) << 6;

    f32x4 acc[4][4];
#pragma unroll
    for (int a = 0; a < 4; ++a)
#pragma unroll
        for (int g = 0; g < 4; ++g) acc[a][g] = (f32x4){0.f, 0.f, 0.f, 0.f};

    const unsigned short* wbs = wsX + (size_t)((l << 7) + woc + m) * 768 + (q << 3);

    for (int ch = 0; ch < 8; ++ch) {
        const int c0 = ch << 5;
        for (int it = tid; it < 520; it += 256) {
            int vidx = it >> 2, g = it & 3;
            int vv = vidx - 1;
            uint4 res = make_uint4(0, 0, 0, 0);
            if ((unsigned)vv < 128u) {
                int k = vv >> 1; int r0, r1; float f0, f1;
                if (vv & 1) { r0 = k; r1 = (k + 1 > 63) ? 63 : k + 1; f0 = 0.75f; f1 = 0.25f; }
                else        { r0 = (k - 1 < 0) ? 0 : k - 1; r1 = k;   f0 = 0.25f; f1 = 0.75f; }
                uint4 u0 = *(const uint4*)(t1 + (((size_t)(n << 12) + (r0 << 6) + xe) << 8) + c0 + (g << 3));
                uint4 u1 = *(const uint4*)(t1 + (((size_t)(n << 12) + (r1 << 6) + xe) << 8) + c0 + (g << 3));
                const unsigned* a0 = (const unsigned*)&u0; const unsigned* a1 = (const unsigned*)&u1;
                unsigned* pr = (unsigned*)&res;
#pragma unroll
                for (int j = 0; j < 4; ++j) {
                    float vl = f0 * bflo(a0[j]) + f1 * bflo(a1[j]);
                    float vh = f0 * bfhi(a0[j]) + f1 * bfhi(a1[j]);
                    pr[j] = (unsigned)f2bf(vl) | ((unsigned)f2bf(vh) << 16);
                }
            }
            *(uint4*)(&ub[vidx * 40 + (g << 3)]) = res;
        }
        __syncthreads();
#pragma unroll
        for (int dv = 0; dv < 3; ++dv) {
            uint4 aq[4];
#pragma unroll
            for (int a = 0; a < 4; ++a)
                aq[a] = *(const uint4*)(wbs + a * (16 * 768) + dv * 256 + c0);
            bf16x8 bfr[4];
#pragma unroll
            for (int g = 0; g < 4; ++g)
                bfr[g] = *(const bf16x8*)(&ub[(woy + (g << 4) + m + dv) * 40 + (q << 3)]);
#pragma unroll
            for (int a = 0; a < 4; ++a) {
                bf16x8 af = __builtin_bit_cast(bf16x8, aq[a]);
#pragma unroll
                for (int g = 0; g < 4; ++g)
                    acc[a][g] = __builtin_amdgcn_mfma_f32_16x16x32_bf16(af, bfr[g], acc[a][g], 0, 0, 0);
            }
        }
        __syncthreads();
    }
#pragma unroll
    for (int a = 0; a < 4; ++a) {
        const int oc = woc + (a << 4) + (q << 2);
#pragma unroll
        for (int g = 0; g < 4; ++g) {
            const int oy = woy + (g << 4) + m;
#pragma unroll
            for (int r = 0; r < 4; ++r) {
                float val = preB[(((size_t)(n << 2) + l) * 128 + oc + r) * 128 + oy] + acc[a][g][r];
                out[(((size_t)(n << 7) + oc + r) * 128 + oy) * 128 + oxl] += lrelu_s(val);
            }
        }
    }
}

// ---------------------------------------------------------------------------
extern "C" void kernel_launch(void* const* d_in, const int* in_sizes, int n_in,
                              void* d_out, int out_size, void* d_ws, size_t ws_size,
                              hipStream_t stream)
{
    const float* x   = (const float*)d_in[0];
    const float* w1  = (const float*)d_in[1];
    const float* b1  = (const float*)d_in[2];
    const float* w2  = (const float*)d_in[3];
    const float* b2  = (const float*)d_in[4];
    const float* wsk = (const float*)d_in[5];
    float* out = (float*)d_out;

    unsigned short* xT  = (unsigned short*)d_ws;        // 8,388,608 sh
    unsigned short* t1  = xT + 8388608;                 // 8,388,608
    unsigned short* t2  = t1 + 8388608;                 // 4,194,304
    unsigned short* w1T = t2 + 4194304;                 // 663,552
    unsigned short* Wp  = w1T + 663552;                 // 3,981,312
    unsigned short* wsX = Wp + 3981312;                 // 393,216
    unsigned short* wsT = wsX + 393216;                 // 32,768
    unsigned short* grd = wsT + 32768;                  // 2,048 sh = 4 KB zero guard
    float* preB = (float*)t2;                            // aliases t2 (dead after k_upskip)

    hipMemsetAsync(grd, 0, 4096, stream);
    k_wt3   <<<2304, 256, 0, stream>>>(w1, w1T);
    k_wphase<<<1536, 256, 0, stream>>>(w2, Wp);
    k_wselx <<<1536, 256, 0, stream>>>(w2, wsX);
    k_wt1   <<<128,  256, 0, stream>>>(wsk, wsT, 32768, 1.0f / 16.0f);
    k_xprep <<<dim3(64, 4, 8), 256, 0, stream>>>(x, xT);
    k_conv1 <<<dim3(256, 4), 256, 0, stream>>>(xT, w1T, b1, t1, grd);
    k_skip  <<<512, 256, 0, stream>>>(xT, wsT, t2);
    k_upskip<<<dim3(8, 128, 8), 256, 0, stream>>>(t2, out);
    k_conv2p<<<dim3(256, 8), 256, 0, stream>>>(t1, Wp, b2, out, preB, grd);
    k_corrx <<<32, 256, 0, stream>>>(t1, wsX, preB, out);
}